// Round 1
// baseline (4908.143 us; speedup 1.0000x reference)
//
#include <hip/hip_runtime.h>
#include <math.h>

typedef unsigned long long ull;

#define MEMD 100
#define RAWD 172
#define TDD  100
#define AGG  472   // 2*MEM + RAW + TD
#define KTOT 572   // AGG + MEM (h appended for the hh-gates)
#define TB   32    // nodes per block
#define NTH  320   // 32 node-lanes x 10 out-lanes
#define QPT  10    // output channels per thread per gate

// ---------------- Phase B: per-node lexicographic argmax over (t, event idx) ----
__global__ void ev_scatter(const int* __restrict__ loc_s, const int* __restrict__ t_s,
                           const int* __restrict__ loc_d, const int* __restrict__ t_d,
                           ull* __restrict__ keys, int E)
{
    int e = blockIdx.x * blockDim.x + threadIdx.x;
    if (e >= 2 * E) return;
    int loc, t;
    if (e < E) { loc = loc_s[e];     t = t_s[e]; }
    else       { loc = loc_d[e - E]; t = t_d[e - E]; }
    // key = (t+1) << 20 | e  -> max over events == lexicographic (t, e) max.
    // t < 2^19, e < 2^20 here; key==0 is the "no event" sentinel.
    ull key = (((ull)(unsigned)(t + 1)) << 20) | (ull)(unsigned)e;
    atomicMax(&keys[loc], key);
}

// ---------------- Phase C: build msg tile + fused GRU -------------------------
// Gate-major GEMM passes (r -> z -> n): each pass keeps only 10 live float4
// weight loads + <=20 accumulators, vs 30 float4 + 40 acc in the fused version.
// Target: VGPR <= ~128 (no scratch), loads pipelined across k-steps.
__global__ __launch_bounds__(NTH, 3)
void tgn_update(const float* __restrict__ memory, const int* __restrict__ last_update,
                const int* __restrict__ n_id,
                const int* __restrict__ dst_s, const float* __restrict__ raw_s,
                const int* __restrict__ dst_d, const float* __restrict__ raw_d,
                const float* __restrict__ time_w, const float* __restrict__ time_b,
                const float* __restrict__ W_ih, const float* __restrict__ W_hh,
                const float* __restrict__ b_ih, const float* __restrict__ b_hh,
                const ull* __restrict__ keys,
                float* __restrict__ out_mem, float* __restrict__ out_lu,
                int N, int E)
{
    // [k][i] layout, +1 pad => stride 33 floats: conflict-free across node lanes
    __shared__ float msg[KTOT][TB + 1];
    __shared__ int   sh_e[TB];
    __shared__ int   sh_dst[TB];
    __shared__ int   sh_src[TB];
    __shared__ float sh_trel[TB];

    const int tid  = threadIdx.x;
    const int base = blockIdx.x * TB;

    if (tid < TB) {
        const int i = tid;
        const int j = base + i;
        int e = -1, dst = 0, src = 0;
        float trel = 0.f;
        if (j < N) {
            src = n_id[j];
            int lu = last_update[src];
            ull key = keys[j];
            if (key != 0ull) {
                e = (int)(key & 0xFFFFFull);
                int te = (int)(key >> 20) - 1;
                trel = (float)(te - lu);
                dst = (e < E) ? dst_s[e] : dst_d[e - E];
                if (te > lu) lu = te;
            }
            out_lu[j] = (float)lu;   // ints < 2^24: exact in f32
        }
        sh_e[i] = e; sh_dst[i] = dst; sh_src[i] = src; sh_trel[i] = trel;
    }
    __syncthreads();

    // --- fill msg tile ---
    // h -> rows [AGG, AGG+100) always; rows [0,100) if node has an event
    for (int idx = tid; idx < TB * MEMD; idx += NTH) {
        int i = idx / MEMD, c = idx % MEMD;
        int j = base + i;
        float v = 0.f;
        if (j < N) v = memory[(size_t)sh_src[i] * MEMD + c];
        msg[AGG + c][i] = v;
        msg[c][i] = (sh_e[i] >= 0) ? v : 0.f;
    }
    // memory[dst] -> rows [100,200)
    for (int idx = tid; idx < TB * MEMD; idx += NTH) {
        int i = idx / MEMD, c = idx % MEMD;
        float v = 0.f;
        if (sh_e[i] >= 0) v = memory[(size_t)sh_dst[i] * MEMD + c];
        msg[MEMD + c][i] = v;
    }
    // raw msg -> rows [200,372)
    for (int idx = tid; idx < TB * RAWD; idx += NTH) {
        int i = idx / RAWD, c = idx % RAWD;
        int e = sh_e[i];
        float v = 0.f;
        if (e >= 0) {
            const float* rp = (e < E) ? (raw_s + (size_t)e * RAWD)
                                      : (raw_d + (size_t)(e - E) * RAWD);
            v = rp[c];
        }
        msg[2 * MEMD + c][i] = v;
    }
    // time encoding -> rows [372,472)
    for (int idx = tid; idx < TB * TDD; idx += NTH) {
        int i = idx / TDD, c = idx % TDD;
        float v = 0.f;
        if (sh_e[i] >= 0) v = cosf(sh_trel[i] * time_w[c] + time_b[c]);
        msg[2 * MEMD + RAWD + c][i] = v;
    }
    __syncthreads();

    // --- register-tiled fp32 GEMM, gate-major passes ---
    const int i  = tid & (TB - 1);   // node lane
    const int g  = tid / TB;         // out-lane 0..9
    const int c0 = g * QPT;

    float rV[QPT], zV[QPT];

    // ---- pass R: r = sigmoid(aggr.Wr + h.Hr + br) over fused K=572 ----
    {
        float acc[QPT];
        #pragma unroll
        for (int q = 0; q < QPT; q++) acc[q] = 0.f;
        const float* W = W_ih + (size_t)c0 * AGG;
        for (int k = 0; k < AGG; k += 4) {
            float m0 = msg[k + 0][i], m1 = msg[k + 1][i];
            float m2 = msg[k + 2][i], m3 = msg[k + 3][i];
            #pragma unroll
            for (int q = 0; q < QPT; q++) {
                float4 w = *(const float4*)(W + (size_t)q * AGG + k);
                acc[q] += m0 * w.x + m1 * w.y + m2 * w.z + m3 * w.w;
            }
        }
        const float* H = W_hh + (size_t)c0 * MEMD;
        for (int k = 0; k < MEMD; k += 4) {
            float m0 = msg[AGG + k + 0][i], m1 = msg[AGG + k + 1][i];
            float m2 = msg[AGG + k + 2][i], m3 = msg[AGG + k + 3][i];
            #pragma unroll
            for (int q = 0; q < QPT; q++) {
                float4 w = *(const float4*)(H + (size_t)q * MEMD + k);
                acc[q] += m0 * w.x + m1 * w.y + m2 * w.z + m3 * w.w;
            }
        }
        #pragma unroll
        for (int q = 0; q < QPT; q++) {
            int c = c0 + q;
            rV[q] = 1.f / (1.f + __expf(-(acc[q] + b_ih[c] + b_hh[c])));
        }
    }

    // ---- pass Z: z = sigmoid(aggr.Wz + h.Hz + bz) ----
    {
        float acc[QPT];
        #pragma unroll
        for (int q = 0; q < QPT; q++) acc[q] = 0.f;
        const float* W = W_ih + (size_t)(MEMD + c0) * AGG;
        for (int k = 0; k < AGG; k += 4) {
            float m0 = msg[k + 0][i], m1 = msg[k + 1][i];
            float m2 = msg[k + 2][i], m3 = msg[k + 3][i];
            #pragma unroll
            for (int q = 0; q < QPT; q++) {
                float4 w = *(const float4*)(W + (size_t)q * AGG + k);
                acc[q] += m0 * w.x + m1 * w.y + m2 * w.z + m3 * w.w;
            }
        }
        const float* H = W_hh + (size_t)(MEMD + c0) * MEMD;
        for (int k = 0; k < MEMD; k += 4) {
            float m0 = msg[AGG + k + 0][i], m1 = msg[AGG + k + 1][i];
            float m2 = msg[AGG + k + 2][i], m3 = msg[AGG + k + 3][i];
            #pragma unroll
            for (int q = 0; q < QPT; q++) {
                float4 w = *(const float4*)(H + (size_t)q * MEMD + k);
                acc[q] += m0 * w.x + m1 * w.y + m2 * w.z + m3 * w.w;
            }
        }
        #pragma unroll
        for (int q = 0; q < QPT; q++) {
            int c = MEMD + c0 + q;
            zV[q] = 1.f / (1.f + __expf(-(acc[q] + b_ih[c] + b_hh[c])));
        }
    }

    // ---- pass N: i_n (over msg) and h_n (over h) kept separate ----
    float aN[QPT], aH[QPT];
    {
        #pragma unroll
        for (int q = 0; q < QPT; q++) { aN[q] = 0.f; aH[q] = 0.f; }
        const float* W = W_ih + (size_t)(2 * MEMD + c0) * AGG;
        for (int k = 0; k < AGG; k += 4) {
            float m0 = msg[k + 0][i], m1 = msg[k + 1][i];
            float m2 = msg[k + 2][i], m3 = msg[k + 3][i];
            #pragma unroll
            for (int q = 0; q < QPT; q++) {
                float4 w = *(const float4*)(W + (size_t)q * AGG + k);
                aN[q] += m0 * w.x + m1 * w.y + m2 * w.z + m3 * w.w;
            }
        }
        const float* H = W_hh + (size_t)(2 * MEMD + c0) * MEMD;
        for (int k = 0; k < MEMD; k += 4) {
            float m0 = msg[AGG + k + 0][i], m1 = msg[AGG + k + 1][i];
            float m2 = msg[AGG + k + 2][i], m3 = msg[AGG + k + 3][i];
            #pragma unroll
            for (int q = 0; q < QPT; q++) {
                float4 w = *(const float4*)(H + (size_t)q * MEMD + k);
                aH[q] += m0 * w.x + m1 * w.y + m2 * w.z + m3 * w.w;
            }
        }
    }

    __syncthreads();   // everyone done reading msg before we overwrite rows [0,100)

    // --- gate epilogue (fully thread-local) ---
    #pragma unroll
    for (int q = 0; q < QPT; q++) {
        int c = c0 + q;
        float r  = rV[q];
        float z  = zV[q];
        float pre = aN[q] + b_ih[2 * MEMD + c] + r * (aH[q] + b_hh[2 * MEMD + c]);
        float ex = __expf(2.f * pre);
        float th = 1.f - 2.f / (ex + 1.f);    // tanh, inf-safe
        float h  = msg[AGG + c][i];
        msg[c][i] = (1.f - z) * th + z * h;
    }
    __syncthreads();

    // coalesced store of new_memory
    for (int idx = tid; idx < TB * MEMD; idx += NTH) {
        int i2 = idx / MEMD, c = idx % MEMD;
        int j = base + i2;
        if (j < N) out_mem[(size_t)j * MEMD + c] = msg[c][i2];
    }
}

extern "C" void kernel_launch(void* const* d_in, const int* in_sizes, int n_in,
                              void* d_out, int out_size, void* d_ws, size_t ws_size,
                              hipStream_t stream)
{
    const float* memory      = (const float*)d_in[0];
    const int*   last_update = (const int*)  d_in[1];
    const int*   n_id        = (const int*)  d_in[2];
    const int*   loc_s       = (const int*)  d_in[3];
    const int*   dst_s       = (const int*)  d_in[4];
    const int*   t_s         = (const int*)  d_in[5];
    const float* raw_s       = (const float*)d_in[6];
    const int*   loc_d       = (const int*)  d_in[7];
    const int*   dst_d       = (const int*)  d_in[8];
    const int*   t_d         = (const int*)  d_in[9];
    const float* raw_d       = (const float*)d_in[10];
    const float* time_w      = (const float*)d_in[11];
    const float* time_b      = (const float*)d_in[12];
    const float* W_ih        = (const float*)d_in[13];
    const float* W_hh        = (const float*)d_in[14];
    const float* b_ih        = (const float*)d_in[15];
    const float* b_hh        = (const float*)d_in[16];

    const int N = in_sizes[2];   // 200000
    const int E = in_sizes[3];   // 100000

    ull*   keys    = (ull*)d_ws;                    // N * 8 bytes
    float* out_mem = (float*)d_out;                 // [N,100]
    float* out_lu  = out_mem + (size_t)N * MEMD;    // [N] (as float)

    hipMemsetAsync(keys, 0, (size_t)N * sizeof(ull), stream);

    ev_scatter<<<(2 * E + 255) / 256, 256, 0, stream>>>(loc_s, t_s, loc_d, t_d, keys, E);

    tgn_update<<<(N + TB - 1) / TB, NTH, 0, stream>>>(
        memory, last_update, n_id,
        dst_s, raw_s, dst_d, raw_d,
        time_w, time_b, W_ih, W_hh, b_ih, b_hh,
        keys, out_mem, out_lu, N, E);
}

// Round 2
// 3403.073 us; speedup vs baseline: 1.4423x; 1.4423x over previous
//
#include <hip/hip_runtime.h>
#include <math.h>

typedef unsigned long long ull;

#define MEMD 100
#define RAWD 172
#define TDD  100
#define AGG  472    // 2*MEM + RAW + TD
#define TB   64     // nodes per block (== wave width: lane i <-> node i)
#define NW   10     // waves per block; wave w owns output channels [w*10, w*10+10) of each gate
#define NTH  640
#define QPT  10
#define LSTR 473    // odd stride: bank = (25*lane + k) % 32 -> conflict-free, 2 lanes/bank

// ---------------- Phase B: per-node lexicographic argmax over (t, event idx) ----
__global__ void ev_scatter(const int* __restrict__ loc_s, const int* __restrict__ t_s,
                           const int* __restrict__ loc_d, const int* __restrict__ t_d,
                           ull* __restrict__ keys, int E)
{
    int e = blockIdx.x * blockDim.x + threadIdx.x;
    if (e >= 2 * E) return;
    int loc, t;
    if (e < E) { loc = loc_s[e];     t = t_s[e]; }
    else       { loc = loc_d[e - E]; t = t_d[e - E]; }
    // key = (t+1) << 20 | e  -> max == lexicographic (t, e) max; 0 = no event.
    ull key = (((ull)(unsigned)(t + 1)) << 20) | (ull)(unsigned)e;
    atomicMax(&keys[loc], key);
}

// ---------------- Phase C: msg tile + fused GRU, scalar-weight GEMM -----------
// lane = node (64/block), wave = 10-channel output group (uniform via readfirstlane)
// => weight addresses are wave-uniform => s_load into SGPRs, zero VMEM in k-loop.
// LDS rows: [0,100)=memory[src] (h, unmasked); [100,200)=memory[dst] (masked);
//           [200,372)=raw (masked); [372,472)=time-enc (masked).
// W-part k<100 uses h*evm in-register (saves 100 duplicated rows).
__global__ __launch_bounds__(NTH, 2)
void tgn_update(const float* __restrict__ memory, const int* __restrict__ last_update,
                const int* __restrict__ n_id,
                const int* __restrict__ dst_s, const float* __restrict__ raw_s,
                const int* __restrict__ dst_d, const float* __restrict__ raw_d,
                const float* __restrict__ time_w, const float* __restrict__ time_b,
                const float* __restrict__ W_ih, const float* __restrict__ W_hh,
                const float* __restrict__ b_ih, const float* __restrict__ b_hh,
                const ull* __restrict__ keys,
                float* __restrict__ out_mem, float* __restrict__ out_lu,
                int N, int E)
{
    __shared__ float L[TB][LSTR];          // 121,088 B
    __shared__ int   sh_e[TB];
    __shared__ int   sh_dst[TB];
    __shared__ int   sh_src[TB];
    __shared__ float sh_trel[TB];

    const int tid  = threadIdx.x;
    const int base = blockIdx.x * TB;

    if (tid < TB) {
        const int i = tid;
        const int j = base + i;
        int e = -1, dst = 0, src = 0;
        float trel = 0.f;
        if (j < N) {
            src = n_id[j];
            int lu = last_update[src];
            ull key = keys[j];
            if (key != 0ull) {
                e = (int)(key & 0xFFFFFull);
                int te = (int)(key >> 20) - 1;
                trel = (float)(te - lu);
                dst = (e < E) ? dst_s[e] : dst_d[e - E];
                if (te > lu) lu = te;
            }
            out_lu[j] = (float)lu;   // ints < 2^24: exact in f32
        }
        sh_e[i] = e; sh_dst[i] = dst; sh_src[i] = src; sh_trel[i] = trel;
    }
    __syncthreads();

    // ---- staging: global -> LDS (coalesced float4 reads, scalar LDS writes) ----
    // rows [0,100): h = memory[src], unmasked
    for (int idx = tid; idx < TB * (MEMD / 4); idx += NTH) {
        int i = idx / (MEMD / 4), q = idx % (MEMD / 4);
        int j = base + i;
        float4 v = make_float4(0.f, 0.f, 0.f, 0.f);
        if (j < N) v = *(const float4*)(memory + (size_t)sh_src[i] * MEMD + q * 4);
        float* p = &L[i][q * 4];
        p[0] = v.x; p[1] = v.y; p[2] = v.z; p[3] = v.w;
    }
    // rows [100,200): memory[dst], masked
    for (int idx = tid; idx < TB * (MEMD / 4); idx += NTH) {
        int i = idx / (MEMD / 4), q = idx % (MEMD / 4);
        float4 v = make_float4(0.f, 0.f, 0.f, 0.f);
        if (sh_e[i] >= 0) v = *(const float4*)(memory + (size_t)sh_dst[i] * MEMD + q * 4);
        float* p = &L[i][MEMD + q * 4];
        p[0] = v.x; p[1] = v.y; p[2] = v.z; p[3] = v.w;
    }
    // rows [200,372): raw msg, masked
    for (int idx = tid; idx < TB * (RAWD / 4); idx += NTH) {
        int i = idx / (RAWD / 4), q = idx % (RAWD / 4);
        int e = sh_e[i];
        float4 v = make_float4(0.f, 0.f, 0.f, 0.f);
        if (e >= 0) {
            const float* rp = (e < E) ? (raw_s + (size_t)e * RAWD)
                                      : (raw_d + (size_t)(e - E) * RAWD);
            v = *(const float4*)(rp + q * 4);
        }
        float* p = &L[i][2 * MEMD + q * 4];
        p[0] = v.x; p[1] = v.y; p[2] = v.z; p[3] = v.w;
    }
    // rows [372,472): time encoding, masked
    for (int idx = tid; idx < TB * (TDD / 4); idx += NTH) {
        int i = idx / (TDD / 4), q = idx % (TDD / 4);
        float tr = sh_trel[i];
        bool  ev = (sh_e[i] >= 0);
        float4 w = *(const float4*)(time_w + q * 4);
        float4 b = *(const float4*)(time_b + q * 4);
        float* p = &L[i][2 * MEMD + RAWD + q * 4];
        p[0] = ev ? cosf(tr * w.x + b.x) : 0.f;
        p[1] = ev ? cosf(tr * w.y + b.y) : 0.f;
        p[2] = ev ? cosf(tr * w.z + b.z) : 0.f;
        p[3] = ev ? cosf(tr * w.w + b.w) : 0.f;
    }
    __syncthreads();

    // ---- GEMM: lane = node, wave = channel group (uniform -> scalar weights) ----
    const int lane = tid & 63;
    const int wv   = __builtin_amdgcn_readfirstlane((int)(tid >> 6));  // 0..9, SGPR
    const int c0   = wv * QPT;
    const float evm = (sh_e[lane] >= 0) ? 1.f : 0.f;
    const float* Lr = &L[lane][0];

    float rV[QPT], zV[QPT], aN[QPT], aH[QPT];

    // ---- fused R+Z pass (shares the LDS m-reads) ----
    {
        float aR[QPT], aZ[QPT];
        #pragma unroll
        for (int q = 0; q < QPT; q++) { aR[q] = 0.f; aZ[q] = 0.f; }
        const float* Wr = W_ih + (size_t)c0 * AGG;
        const float* Wz = W_ih + (size_t)(MEMD + c0) * AGG;
        for (int k = 0; k < MEMD; k += 4) {           // msg rows 0..99 = h * evm
            float m0 = Lr[k] * evm, m1 = Lr[k + 1] * evm;
            float m2 = Lr[k + 2] * evm, m3 = Lr[k + 3] * evm;
            #pragma unroll
            for (int q = 0; q < QPT; q++) {
                float4 a = *(const float4*)(Wr + (size_t)q * AGG + k);
                float4 b = *(const float4*)(Wz + (size_t)q * AGG + k);
                aR[q] += m0 * a.x + m1 * a.y + m2 * a.z + m3 * a.w;
                aZ[q] += m0 * b.x + m1 * b.y + m2 * b.z + m3 * b.w;
            }
        }
        for (int k = MEMD; k < AGG; k += 4) {         // msg rows 100..471 (pre-masked)
            float m0 = Lr[k], m1 = Lr[k + 1], m2 = Lr[k + 2], m3 = Lr[k + 3];
            #pragma unroll
            for (int q = 0; q < QPT; q++) {
                float4 a = *(const float4*)(Wr + (size_t)q * AGG + k);
                float4 b = *(const float4*)(Wz + (size_t)q * AGG + k);
                aR[q] += m0 * a.x + m1 * a.y + m2 * a.z + m3 * a.w;
                aZ[q] += m0 * b.x + m1 * b.y + m2 * b.z + m3 * b.w;
            }
        }
        const float* Hr = W_hh + (size_t)c0 * MEMD;
        const float* Hz = W_hh + (size_t)(MEMD + c0) * MEMD;
        for (int k = 0; k < MEMD; k += 4) {           // h rows, unmasked
            float m0 = Lr[k], m1 = Lr[k + 1], m2 = Lr[k + 2], m3 = Lr[k + 3];
            #pragma unroll
            for (int q = 0; q < QPT; q++) {
                float4 a = *(const float4*)(Hr + (size_t)q * MEMD + k);
                float4 b = *(const float4*)(Hz + (size_t)q * MEMD + k);
                aR[q] += m0 * a.x + m1 * a.y + m2 * a.z + m3 * a.w;
                aZ[q] += m0 * b.x + m1 * b.y + m2 * b.z + m3 * b.w;
            }
        }
        #pragma unroll
        for (int q = 0; q < QPT; q++) {
            int c = c0 + q;
            rV[q] = 1.f / (1.f + __expf(-(aR[q] + b_ih[c] + b_hh[c])));
            zV[q] = 1.f / (1.f + __expf(-(aZ[q] + b_ih[MEMD + c] + b_hh[MEMD + c])));
        }
    }

    // ---- N pass: i_n over msg, h_n over h (kept separate) ----
    {
        #pragma unroll
        for (int q = 0; q < QPT; q++) { aN[q] = 0.f; aH[q] = 0.f; }
        const float* Wn = W_ih + (size_t)(2 * MEMD + c0) * AGG;
        for (int k = 0; k < MEMD; k += 4) {
            float m0 = Lr[k] * evm, m1 = Lr[k + 1] * evm;
            float m2 = Lr[k + 2] * evm, m3 = Lr[k + 3] * evm;
            #pragma unroll
            for (int q = 0; q < QPT; q++) {
                float4 a = *(const float4*)(Wn + (size_t)q * AGG + k);
                aN[q] += m0 * a.x + m1 * a.y + m2 * a.z + m3 * a.w;
            }
        }
        for (int k = MEMD; k < AGG; k += 4) {
            float m0 = Lr[k], m1 = Lr[k + 1], m2 = Lr[k + 2], m3 = Lr[k + 3];
            #pragma unroll
            for (int q = 0; q < QPT; q++) {
                float4 a = *(const float4*)(Wn + (size_t)q * AGG + k);
                aN[q] += m0 * a.x + m1 * a.y + m2 * a.z + m3 * a.w;
            }
        }
        const float* Hn = W_hh + (size_t)(2 * MEMD + c0) * MEMD;
        for (int k = 0; k < MEMD; k += 4) {
            float m0 = Lr[k], m1 = Lr[k + 1], m2 = Lr[k + 2], m3 = Lr[k + 3];
            #pragma unroll
            for (int q = 0; q < QPT; q++) {
                float4 a = *(const float4*)(Hn + (size_t)q * MEMD + k);
                aH[q] += m0 * a.x + m1 * a.y + m2 * a.z + m3 * a.w;
            }
        }
    }

    __syncthreads();   // all waves done reading msg rows before reuse of [100,200)

    // ---- gate epilogue: write new_memory into rows [100,200) ----
    #pragma unroll
    for (int q = 0; q < QPT; q++) {
        int c = c0 + q;
        float r  = rV[q];
        float z  = zV[q];
        float pre = aN[q] + b_ih[2 * MEMD + c] + r * (aH[q] + b_hh[2 * MEMD + c]);
        float ex = __expf(2.f * pre);
        float th = 1.f - 2.f / (ex + 1.f);    // tanh, inf-safe
        float h  = Lr[c];                     // rows [0,100) = h, untouched
        L[lane][MEMD + c] = (1.f - z) * th + z * h;
    }
    __syncthreads();

    // coalesced float4 store of new_memory
    for (int idx = tid; idx < TB * (MEMD / 4); idx += NTH) {
        int i = idx / (MEMD / 4), q = idx % (MEMD / 4);
        int j = base + i;
        if (j < N) {
            const float* p = &L[i][MEMD + q * 4];
            float4 v; v.x = p[0]; v.y = p[1]; v.z = p[2]; v.w = p[3];
            *(float4*)(out_mem + (size_t)j * MEMD + q * 4) = v;
        }
    }
}

extern "C" void kernel_launch(void* const* d_in, const int* in_sizes, int n_in,
                              void* d_out, int out_size, void* d_ws, size_t ws_size,
                              hipStream_t stream)
{
    const float* memory      = (const float*)d_in[0];
    const int*   last_update = (const int*)  d_in[1];
    const int*   n_id        = (const int*)  d_in[2];
    const int*   loc_s       = (const int*)  d_in[3];
    const int*   dst_s       = (const int*)  d_in[4];
    const int*   t_s         = (const int*)  d_in[5];
    const float* raw_s       = (const float*)d_in[6];
    const int*   loc_d       = (const int*)  d_in[7];
    const int*   dst_d       = (const int*)  d_in[8];
    const int*   t_d         = (const int*)  d_in[9];
    const float* raw_d       = (const float*)d_in[10];
    const float* time_w      = (const float*)d_in[11];
    const float* time_b      = (const float*)d_in[12];
    const float* W_ih        = (const float*)d_in[13];
    const float* W_hh        = (const float*)d_in[14];
    const float* b_ih        = (const float*)d_in[15];
    const float* b_hh        = (const float*)d_in[16];

    const int N = in_sizes[2];   // 200000
    const int E = in_sizes[3];   // 100000

    ull*   keys    = (ull*)d_ws;                    // N * 8 bytes
    float* out_mem = (float*)d_out;                 // [N,100]
    float* out_lu  = out_mem + (size_t)N * MEMD;    // [N] (as float)

    hipMemsetAsync(keys, 0, (size_t)N * sizeof(ull), stream);

    ev_scatter<<<(2 * E + 255) / 256, 256, 0, stream>>>(loc_s, t_s, loc_d, t_d, keys, E);

    tgn_update<<<(N + TB - 1) / TB, NTH, 0, stream>>>(
        memory, last_update, n_id,
        dst_s, raw_s, dst_d, raw_d,
        time_w, time_b, W_ih, W_hh, b_ih, b_hh,
        keys, out_mem, out_lu, N, E);
}

// Round 3
// 1116.280 us; speedup vs baseline: 4.3969x; 3.0486x over previous
//
#include <hip/hip_runtime.h>
#include <math.h>

typedef unsigned long long ull;
typedef unsigned short u16;

#define MEMD 100
#define RAWD 172
#define AGG  472    // 2*MEM + RAW + TD
#define KTOT 572    // AGG + MEM
#define KPAD 576    // 18 * 32
#define NCOL 400    // r(100) z(100) i_n(100) h_n(100)
#define TB   64     // nodes per block
#define NTH  512    // 8 waves
#define AST  584    // A row stride (bf16 elems): 1168B, 16B-divisible, breaks bank pattern
#define OST  404    // epilogue out row stride (f32): 1616B, 16B-divisible

typedef float f32x4 __attribute__((ext_vector_type(4)));
typedef short v8s   __attribute__((ext_vector_type(8)));   // 8 x bf16 payload

__device__ inline u16 f2bf(float x) {
    unsigned u = __float_as_uint(x);
    unsigned r = u + 0x7FFFu + ((u >> 16) & 1u);   // RNE
    return (u16)(r >> 16);
}
__device__ inline float bf2f(u16 h) { return __uint_as_float(((unsigned)h) << 16); }

// ---------------- Phase A: pack B = [KPAD x NCOL] bf16 hi/lo, col-major ------
// col c: 0..99=r, 100..199=z, 200..299=i_n, 300..399=h_n
// rows k: 0..471 = W_ih part, 472..571 = W_hh part, 572..575 = 0
__global__ void prep_B(const float* __restrict__ W_ih, const float* __restrict__ W_hh,
                       u16* __restrict__ BT_hi, u16* __restrict__ BT_lo)
{
    int idx = blockIdx.x * 256 + threadIdx.x;
    if (idx >= NCOL * KPAD) return;
    int c = idx / KPAD, k = idx % KPAD;
    float v = 0.f;
    if (c < 200) {                       // r, z rows: fused W_ih | W_hh
        if (k < AGG)        v = W_ih[(size_t)c * AGG + k];
        else if (k < KTOT)  v = W_hh[(size_t)c * MEMD + (k - AGG)];
    } else if (c < 300) {                // i_n: W_ih only
        if (k < AGG)        v = W_ih[(size_t)c * AGG + k];
    } else {                             // h_n: W_hh rows 200..299 only
        if (k >= AGG && k < KTOT) v = W_hh[(size_t)(c - 100) * MEMD + (k - AGG)];
    }
    u16 h = f2bf(v);
    float vh = bf2f(h);
    BT_hi[idx] = h;
    BT_lo[idx] = f2bf(v - vh);
}

// ---------------- Phase B: per-node lexicographic argmax over (t, event idx) ----
__global__ void ev_scatter(const int* __restrict__ loc_s, const int* __restrict__ t_s,
                           const int* __restrict__ loc_d, const int* __restrict__ t_d,
                           ull* __restrict__ keys, int E)
{
    int e = blockIdx.x * blockDim.x + threadIdx.x;
    if (e >= 2 * E) return;
    int loc, t;
    if (e < E) { loc = loc_s[e];     t = t_s[e]; }
    else       { loc = loc_d[e - E]; t = t_d[e - E]; }
    ull key = (((ull)(unsigned)(t + 1)) << 20) | (ull)(unsigned)e;
    atomicMax(&keys[loc], key);
}

// ---------------- Phase C: msg tile (bf16 hi/lo) + MFMA GEMM + GRU epilogue ---
// A[node][k]: k<100 memory[src]*ev, 100..199 memory[dst]*ev, 200..371 raw*ev,
//             372..471 timeenc*ev, 472..571 memory[src] (h, unmasked), 572..575 = 0
// 3-product bf16 split: D += Ah*Bh + Al*Bh + Ah*Bl  (~fp32 accuracy)
__global__ __launch_bounds__(NTH)
void tgn_update(const float* __restrict__ memory, const int* __restrict__ last_update,
                const int* __restrict__ n_id,
                const int* __restrict__ dst_s, const float* __restrict__ raw_s,
                const int* __restrict__ dst_d, const float* __restrict__ raw_d,
                const float* __restrict__ time_w, const float* __restrict__ time_b,
                const float* __restrict__ b_ih, const float* __restrict__ b_hh,
                const u16* __restrict__ BT_hi, const u16* __restrict__ BT_lo,
                const ull* __restrict__ keys,
                float* __restrict__ out_mem, float* __restrict__ out_lu,
                int N, int E)
{
    __shared__ __align__(16) u16 SH[2][TB][AST];   // [0]=hi [1]=lo, 149504 B
    __shared__ int   sh_e[TB];
    __shared__ int   sh_dst[TB];
    __shared__ int   sh_src[TB];
    __shared__ float sh_trel[TB];

    const int tid  = threadIdx.x;
    const int base = blockIdx.x * TB;
    float* outF = (float*)&SH[0][0][0];            // reused after GEMM

    if (tid < TB) {
        const int i = tid;
        const int j = base + i;
        int e = -1, dst = 0, src = 0;
        float trel = 0.f;
        if (j < N) {
            src = n_id[j];
            int lu = last_update[src];
            ull key = keys[j];
            if (key != 0ull) {
                e = (int)(key & 0xFFFFFull);
                int te = (int)(key >> 20) - 1;
                trel = (float)(te - lu);
                dst = (e < E) ? dst_s[e] : dst_d[e - E];
                if (te > lu) lu = te;
            }
            out_lu[j] = (float)lu;
        }
        sh_e[i] = e; sh_dst[i] = dst; sh_src[i] = src; sh_trel[i] = trel;
    }
    __syncthreads();

    // ---- staging: gather fp32, convert to bf16 hi/lo, write LDS ----
    #define CVT4(v, h4, l4)                                            \
        { u16 h0=f2bf(v.x),h1=f2bf(v.y),h2=f2bf(v.z),h3=f2bf(v.w);     \
          h4 = make_ushort4(h0,h1,h2,h3);                              \
          l4 = make_ushort4(f2bf(v.x-bf2f(h0)), f2bf(v.y-bf2f(h1)),    \
                            f2bf(v.z-bf2f(h2)), f2bf(v.w-bf2f(h3))); }

    const ushort4 Z4 = make_ushort4(0,0,0,0);

    // (a) memory[src]: h rows 472.. (unmasked) + msg rows 0.. (masked)
    for (int idx = tid; idx < TB * 25; idx += NTH) {
        int i = idx / 25, q = idx % 25;
        int j = base + i;
        float4 v = make_float4(0.f,0.f,0.f,0.f);
        if (j < N) v = *(const float4*)(memory + (size_t)sh_src[i] * MEMD + q * 4);
        ushort4 h4, l4; CVT4(v, h4, l4);
        *(ushort4*)&SH[0][i][AGG + q*4] = h4;
        *(ushort4*)&SH[1][i][AGG + q*4] = l4;
        bool ev = (sh_e[i] >= 0);
        *(ushort4*)&SH[0][i][q*4] = ev ? h4 : Z4;
        *(ushort4*)&SH[1][i][q*4] = ev ? l4 : Z4;
    }
    // (b) memory[dst]: rows 100..199, masked
    for (int idx = tid; idx < TB * 25; idx += NTH) {
        int i = idx / 25, q = idx % 25;
        float4 v = make_float4(0.f,0.f,0.f,0.f);
        if (sh_e[i] >= 0) v = *(const float4*)(memory + (size_t)sh_dst[i] * MEMD + q * 4);
        ushort4 h4, l4; CVT4(v, h4, l4);
        *(ushort4*)&SH[0][i][MEMD + q*4] = h4;
        *(ushort4*)&SH[1][i][MEMD + q*4] = l4;
    }
    // (c) raw: rows 200..371, masked
    for (int idx = tid; idx < TB * 43; idx += NTH) {
        int i = idx / 43, q = idx % 43;
        int e = sh_e[i];
        float4 v = make_float4(0.f,0.f,0.f,0.f);
        if (e >= 0) {
            const float* rp = (e < E) ? (raw_s + (size_t)e * RAWD)
                                      : (raw_d + (size_t)(e - E) * RAWD);
            v = *(const float4*)(rp + q * 4);
        }
        ushort4 h4, l4; CVT4(v, h4, l4);
        *(ushort4*)&SH[0][i][2*MEMD + q*4] = h4;
        *(ushort4*)&SH[1][i][2*MEMD + q*4] = l4;
    }
    // (d) time enc: rows 372..471, masked
    for (int idx = tid; idx < TB * 25; idx += NTH) {
        int i = idx / 25, q = idx % 25;
        float tr = sh_trel[i];
        bool  ev = (sh_e[i] >= 0);
        float4 w = *(const float4*)(time_w + q * 4);
        float4 b = *(const float4*)(time_b + q * 4);
        float4 v;
        v.x = ev ? cosf(tr * w.x + b.x) : 0.f;
        v.y = ev ? cosf(tr * w.y + b.y) : 0.f;
        v.z = ev ? cosf(tr * w.z + b.z) : 0.f;
        v.w = ev ? cosf(tr * w.w + b.w) : 0.f;
        ushort4 h4, l4; CVT4(v, h4, l4);
        *(ushort4*)&SH[0][i][2*MEMD + RAWD + q*4] = h4;
        *(ushort4*)&SH[1][i][2*MEMD + RAWD + q*4] = l4;
    }
    // (e) zero pad k = 572..575
    for (int i = tid; i < TB; i += NTH) {
        *(ushort4*)&SH[0][i][KTOT] = Z4;
        *(ushort4*)&SH[1][i][KTOT] = Z4;
    }
    __syncthreads();

    // ---- MFMA GEMM: wave wv owns ch-tiles {wv, wv+8, wv+16} (+24 for wv==0) ----
    const int lane = tid & 63;
    const int wv   = __builtin_amdgcn_readfirstlane(tid >> 6);   // 0..7

    f32x4 acc[4][4];
    #pragma unroll
    for (int s = 0; s < 4; s++)
        #pragma unroll
        for (int nt = 0; nt < 4; nt++)
            acc[s][nt] = (f32x4){0.f, 0.f, 0.f, 0.f};

    const int arow = lane & 15;              // row-in-tile
    const int koff = (lane >> 4) << 3;       // 0,8,16,24

    for (int ks = 0; ks < KPAD / 32; ks++) {
        const int k0 = ks * 32 + koff;
        v8s ah[4], al[4];
        #pragma unroll
        for (int nt = 0; nt < 4; nt++) {
            ah[nt] = *(const v8s*)&SH[0][nt * 16 + arow][k0];
            al[nt] = *(const v8s*)&SH[1][nt * 16 + arow][k0];
        }
        #pragma unroll
        for (int s = 0; s < 4; s++) {
            if (s == 3 && wv != 0) continue;
            const int ct = (s < 3) ? (wv + 8 * s) : 24;
            // zero-tile skips: pure-i_n tiles (ct 13..17) dead for ks>=15;
            // pure-h_n tiles (ct 19..24) dead for ks<14
            if (ct >= 13 && ct <= 17 && ks >= 15) continue;
            if (ct >= 19 && ks < 14) continue;
            const size_t boff = (size_t)(ct * 16 + arow) * KPAD + k0;
            v8s bh = *(const v8s*)(BT_hi + boff);
            v8s bl = *(const v8s*)(BT_lo + boff);
            #pragma unroll
            for (int nt = 0; nt < 4; nt++) {
                acc[s][nt] = __builtin_amdgcn_mfma_f32_16x16x32_bf16(ah[nt], bh, acc[s][nt], 0, 0, 0);
                acc[s][nt] = __builtin_amdgcn_mfma_f32_16x16x32_bf16(al[nt], bh, acc[s][nt], 0, 0, 0);
                acc[s][nt] = __builtin_amdgcn_mfma_f32_16x16x32_bf16(ah[nt], bl, acc[s][nt], 0, 0, 0);
            }
        }
    }

    // ---- epilogue ----
    // preload h (fp32-exact via hi+lo) before SH is overwritten by outF
    const int ei = tid & 63;
    const int eg = tid >> 6;
    float hval[13];
    #pragma unroll
    for (int q = 0; q < 13; q++) {
        int c = eg + 8 * q;
        hval[q] = 0.f;
        if (c < MEMD)
            hval[q] = bf2f(SH[0][ei][AGG + c]) + bf2f(SH[1][ei][AGG + c]);
    }
    __syncthreads();

    // dump accumulators: D layout col=lane&15, row=(lane>>4)*4+reg  [m89]
    {
        const int rb = (lane >> 4) << 2;
        #pragma unroll
        for (int s = 0; s < 4; s++) {
            if (s == 3 && wv != 0) continue;
            const int ct  = (s < 3) ? (wv + 8 * s) : 24;
            const int col = ct * 16 + (lane & 15);
            #pragma unroll
            for (int nt = 0; nt < 4; nt++) {
                const int row = nt * 16 + rb;
                #pragma unroll
                for (int p = 0; p < 4; p++)
                    outF[(row + p) * OST + col] = acc[s][nt][p];
            }
        }
    }
    __syncthreads();

    // gates: r=sig(o[c]+bi+bh), z=sig(o[100+c]+..), n=tanh(o[200+c]+bi + r*(o[300+c]+bh))
    #pragma unroll
    for (int q = 0; q < 13; q++) {
        int c = eg + 8 * q;
        if (c < MEMD) {
            const float* row = outF + ei * OST;
            float rr = 1.f / (1.f + __expf(-(row[c]        + b_ih[c]        + b_hh[c])));
            float zz = 1.f / (1.f + __expf(-(row[MEMD + c] + b_ih[MEMD + c] + b_hh[MEMD + c])));
            float pre = row[2*MEMD + c] + b_ih[2*MEMD + c] + rr * (row[3*MEMD + c] + b_hh[2*MEMD + c]);
            float ex = __expf(2.f * pre);
            float th = 1.f - 2.f / (ex + 1.f);      // tanh, inf-safe
            outF[ei * OST + c] = (1.f - zz) * th + zz * hval[q];
        }
    }
    __syncthreads();

    // coalesced float4 store of new_memory
    for (int idx = tid; idx < TB * 25; idx += NTH) {
        int i = idx / 25, q = idx % 25;
        int j = base + i;
        if (j < N) {
            float4 v = *(const float4*)(outF + i * OST + q * 4);
            *(float4*)(out_mem + (size_t)j * MEMD + q * 4) = v;
        }
    }
}

extern "C" void kernel_launch(void* const* d_in, const int* in_sizes, int n_in,
                              void* d_out, int out_size, void* d_ws, size_t ws_size,
                              hipStream_t stream)
{
    const float* memory      = (const float*)d_in[0];
    const int*   last_update = (const int*)  d_in[1];
    const int*   n_id        = (const int*)  d_in[2];
    const int*   loc_s       = (const int*)  d_in[3];
    const int*   dst_s       = (const int*)  d_in[4];
    const int*   t_s         = (const int*)  d_in[5];
    const float* raw_s       = (const float*)d_in[6];
    const int*   loc_d       = (const int*)  d_in[7];
    const int*   dst_d       = (const int*)  d_in[8];
    const int*   t_d         = (const int*)  d_in[9];
    const float* raw_d       = (const float*)d_in[10];
    const float* time_w      = (const float*)d_in[11];
    const float* time_b      = (const float*)d_in[12];
    const float* W_ih        = (const float*)d_in[13];
    const float* W_hh        = (const float*)d_in[14];
    const float* b_ih        = (const float*)d_in[15];
    const float* b_hh        = (const float*)d_in[16];

    const int N = in_sizes[2];   // 200000
    const int E = in_sizes[3];   // 100000

    ull* keys   = (ull*)d_ws;                                   // N*8 B
    u16* BT_hi  = (u16*)((char*)d_ws + (size_t)N * 8);          // 400*576*2 B
    u16* BT_lo  = BT_hi + (size_t)NCOL * KPAD;                  // 400*576*2 B
    float* out_mem = (float*)d_out;
    float* out_lu  = out_mem + (size_t)N * MEMD;

    hipMemsetAsync(keys, 0, (size_t)N * sizeof(ull), stream);

    prep_B<<<(NCOL * KPAD + 255) / 256, 256, 0, stream>>>(W_ih, W_hh, BT_hi, BT_lo);

    ev_scatter<<<(2 * E + 255) / 256, 256, 0, stream>>>(loc_s, t_s, loc_d, t_d, keys, E);

    tgn_update<<<(N + TB - 1) / TB, NTH, 0, stream>>>(
        memory, last_update, n_id,
        dst_s, raw_s, dst_d, raw_d,
        time_w, time_b, b_ih, b_hh,
        BT_hi, BT_lo,
        keys, out_mem, out_lu, N, E);
}